// Round 1
// baseline (1750.284 us; speedup 1.0000x reference)
//
#include <hip/hip_runtime.h>
#include <hip/hip_bf16.h>
#include <cstdint>
#include <cstddef>

#define NUM_TOKENS 4096
#define HIDDEN     2048
#define INTER      4096
#define NEXP       8

#define BM 128
#define BN 128
#define BK 32
#define LDSS (BK + 8)   // LDS row stride in bf16 elems (+8 pad breaks bank aliasing, keeps 16B align)

typedef __attribute__((ext_vector_type(8))) short  short8;
typedef __attribute__((ext_vector_type(4))) float  float4v;

// workspace layout (int-indexed for meta/routing, byte offset for act)
#define M_CNT 0
#define M_CUR 8
#define M_OFF 16
#define META_INTS 64
#define EID_OFF   64
#define TGATE_OFF (EID_OFF + 2*NUM_TOKENS)
#define PERM_OFF  (TGATE_OFF + 2*NUM_TOKENS)
#define PGATE_OFF (PERM_OFF + 2*NUM_TOKENS)
#define ACT_BYTE_OFF (256*1024)

__device__ __forceinline__ short f2bf(float x){
  union { __hip_bfloat16 h; short s; } u;
  u.h = __float2bfloat16(x);
  return u.s;
}

__device__ __forceinline__ short8 pack8(float4 lo, float4 hi){
  short8 r;
  r[0]=f2bf(lo.x); r[1]=f2bf(lo.y); r[2]=f2bf(lo.z); r[3]=f2bf(lo.w);
  r[4]=f2bf(hi.x); r[5]=f2bf(hi.y); r[6]=f2bf(hi.z); r[7]=f2bf(hi.w);
  return r;
}

// ---------------- routing: top-2 of 8 logits; gates via 2-way softmax ----------------
__global__ void routing_kernel(const float* __restrict__ logits,
                               int* __restrict__ ws_i, float* __restrict__ ws_f){
  int t = blockIdx.x * blockDim.x + threadIdx.x;
  if (t >= NUM_TOKENS) return;
  float l[NEXP];
  #pragma unroll
  for (int i = 0; i < NEXP; ++i) l[i] = logits[t*NEXP + i];
  int i1 = 0; float b1 = l[0];
  #pragma unroll
  for (int i = 1; i < NEXP; ++i) if (l[i] > b1){ b1 = l[i]; i1 = i; }
  int i2 = -1; float b2 = -3.4e38f;
  #pragma unroll
  for (int i = 0; i < NEXP; ++i) if (i != i1 && l[i] > b2){ b2 = l[i]; i2 = i; }
  // renormalized top-2 softmax weights depend only on the two top logits
  float w1 = 1.f / (1.f + __expf(b2 - b1));
  float w2 = 1.f - w1;
  ws_i[EID_OFF + 2*t]     = i1;
  ws_i[EID_OFF + 2*t + 1] = i2;
  ws_f[TGATE_OFF + 2*t]     = w1;
  ws_f[TGATE_OFF + 2*t + 1] = w2;
  atomicAdd(&ws_i[M_CNT + i1], 1);
  atomicAdd(&ws_i[M_CNT + i2], 1);
}

__global__ void scan_kernel(int* __restrict__ ws_i){
  if (threadIdx.x == 0){
    int s = 0;
    for (int e = 0; e < NEXP; ++e){
      ws_i[M_OFF + e] = s;
      ws_i[M_CUR + e] = s;
      s += ws_i[M_CNT + e];
    }
    ws_i[M_OFF + NEXP] = s;
  }
}

__global__ void scatter_kernel(int* __restrict__ ws_i, float* __restrict__ ws_f){
  int t = blockIdx.x * blockDim.x + threadIdx.x;
  if (t >= NUM_TOKENS) return;
  #pragma unroll
  for (int k = 0; k < 2; ++k){
    int e = ws_i[EID_OFF + 2*t + k];
    int pos = atomicAdd(&ws_i[M_CUR + e], 1);
    ws_i[PERM_OFF + pos]  = t;
    ws_f[PGATE_OFF + pos] = ws_f[TGATE_OFF + 2*t + k];
  }
}

// ---------------- GEMM1: act = silu(h @ w13g^T) * (h @ w13u^T), bf16 out ----------------
__global__ __launch_bounds__(256, 2) void gemm1_kernel(
    const float* __restrict__ hidden, const float* __restrict__ w13,
    const int* __restrict__ ws_i, __hip_bfloat16* __restrict__ act)
{
  const int e   = blockIdx.z;
  const int cnt = ws_i[M_CNT + e];
  const int m0  = blockIdx.y * BM;
  if (m0 >= cnt) return;
  const int off = ws_i[M_OFF + e];
  const int n0  = blockIdx.x * BN;
  const float* wbase = w13 + (size_t)e * (2*INTER) * HIDDEN;

  __shared__ short sA [BM*LDSS];
  __shared__ short sBg[BN*LDSS];
  __shared__ short sBu[BN*LDSS];

  const int tid  = threadIdx.x;
  const int srow = tid >> 1;          // 0..127
  const int scol = (tid & 1) * 16;    // 0 or 16 (floats)

  int arow = m0 + srow; if (arow >= cnt) arow = cnt - 1;
  const int tok = ws_i[PERM_OFF + off + arow];
  const float* aptr = hidden + (size_t)tok * HIDDEN + scol;
  const float* gptr = wbase + (size_t)(n0 + srow) * HIDDEN + scol;
  const float* uptr = wbase + (size_t)(INTER + n0 + srow) * HIDDEN + scol;

  const int wave = tid >> 6;
  const int lane = tid & 63;
  const int wm = (wave & 1) * 64;
  const int wn = (wave >> 1) * 64;
  const int lr = lane & 15;
  const int kq = (lane >> 4) * 8;

  float4v accg[4][4], accu[4][4];
  #pragma unroll
  for (int i = 0; i < 4; ++i)
    #pragma unroll
    for (int j = 0; j < 4; ++j)
      #pragma unroll
      for (int r = 0; r < 4; ++r){ accg[i][j][r] = 0.f; accu[i][j][r] = 0.f; }

  for (int k0 = 0; k0 < HIDDEN; k0 += BK){
    const float4* a4 = (const float4*)(aptr + k0);
    const float4* g4 = (const float4*)(gptr + k0);
    const float4* u4 = (const float4*)(uptr + k0);
    float4 a0=a4[0], a1=a4[1], a2=a4[2], a3=a4[3];
    float4 g0=g4[0], g1=g4[1], g2=g4[2], g3=g4[3];
    float4 u0=u4[0], u1=u4[1], u2=u4[2], u3=u4[3];

    __syncthreads();   // previous iteration's compute done reading LDS
    *(short8*)&sA [srow*LDSS + scol]     = pack8(a0, a1);
    *(short8*)&sA [srow*LDSS + scol + 8] = pack8(a2, a3);
    *(short8*)&sBg[srow*LDSS + scol]     = pack8(g0, g1);
    *(short8*)&sBg[srow*LDSS + scol + 8] = pack8(g2, g3);
    *(short8*)&sBu[srow*LDSS + scol]     = pack8(u0, u1);
    *(short8*)&sBu[srow*LDSS + scol + 8] = pack8(u2, u3);
    __syncthreads();

    short8 af[4], bg[4], bu[4];
    #pragma unroll
    for (int mi = 0; mi < 4; ++mi)
      af[mi] = *(const short8*)&sA[(wm + mi*16 + lr)*LDSS + kq];
    #pragma unroll
    for (int ni = 0; ni < 4; ++ni){
      bg[ni] = *(const short8*)&sBg[(wn + ni*16 + lr)*LDSS + kq];
      bu[ni] = *(const short8*)&sBu[(wn + ni*16 + lr)*LDSS + kq];
    }
    #pragma unroll
    for (int mi = 0; mi < 4; ++mi)
      #pragma unroll
      for (int ni = 0; ni < 4; ++ni){
        accg[mi][ni] = __builtin_amdgcn_mfma_f32_16x16x32_bf16(af[mi], bg[ni], accg[mi][ni], 0, 0, 0);
        accu[mi][ni] = __builtin_amdgcn_mfma_f32_16x16x32_bf16(af[mi], bu[ni], accu[mi][ni], 0, 0, 0);
      }
  }

  // epilogue: silu(g)*u, write bf16 act rows (C layout: col=lane&15, row=(lane>>4)*4+r)
  const int rq = (lane >> 4) * 4;
  #pragma unroll
  for (int mi = 0; mi < 4; ++mi){
    #pragma unroll
    for (int r = 0; r < 4; ++r){
      int gm = m0 + wm + mi*16 + rq + r;
      if (gm >= cnt) continue;
      __hip_bfloat16* arow_ptr = act + (size_t)(off + gm) * INTER + n0;
      #pragma unroll
      for (int ni = 0; ni < 4; ++ni){
        float g = accg[mi][ni][r];
        float u = accu[mi][ni][r];
        float s = g / (1.f + __expf(-g)) * u;
        arow_ptr[wn + ni*16 + lr] = __float2bfloat16(s);
      }
    }
  }
}

// ---------------- GEMM2: out[tok] += gate * (act @ w2^T) ----------------
__global__ __launch_bounds__(256, 2) void gemm2_kernel(
    const __hip_bfloat16* __restrict__ act, const float* __restrict__ w2,
    const int* __restrict__ ws_i, const float* __restrict__ ws_f,
    float* __restrict__ out)
{
  const int e   = blockIdx.z;
  const int cnt = ws_i[M_CNT + e];
  const int m0  = blockIdx.y * BM;
  if (m0 >= cnt) return;
  const int off = ws_i[M_OFF + e];
  const int n0  = blockIdx.x * BN;
  const float* wbase = w2 + (size_t)e * HIDDEN * INTER;

  __shared__ short sA[BM*LDSS];
  __shared__ short sB[BN*LDSS];
  __shared__ int   s_tok[BM];
  __shared__ float s_gate[BM];

  const int tid  = threadIdx.x;
  const int srow = tid >> 1;
  const int scol = (tid & 1) * 16;

  int arow = m0 + srow; if (arow >= cnt) arow = cnt - 1;
  const __hip_bfloat16* aptr = act + (size_t)(off + arow) * INTER + scol;
  const float* bptr = wbase + (size_t)(n0 + srow) * INTER + scol;

  if (tid < BM){
    int r = m0 + tid;
    if (r < cnt){
      s_tok[tid]  = ws_i[PERM_OFF + off + r];
      s_gate[tid] = ws_f[PGATE_OFF + off + r];
    }
  }

  const int wave = tid >> 6;
  const int lane = tid & 63;
  const int wm = (wave & 1) * 64;
  const int wn = (wave >> 1) * 64;
  const int lr = lane & 15;
  const int kq = (lane >> 4) * 8;

  float4v acc[4][4];
  #pragma unroll
  for (int i = 0; i < 4; ++i)
    #pragma unroll
    for (int j = 0; j < 4; ++j)
      #pragma unroll
      for (int r = 0; r < 4; ++r) acc[i][j][r] = 0.f;

  for (int k0 = 0; k0 < INTER; k0 += BK){
    const uint4* a16 = (const uint4*)(aptr + k0);   // 8 bf16 per uint4
    uint4 av0 = a16[0], av1 = a16[1];
    const float4* b4 = (const float4*)(bptr + k0);
    float4 b0=b4[0], b1=b4[1], b2=b4[2], b3=b4[3];

    __syncthreads();
    *(uint4*)&sA[srow*LDSS + scol]      = av0;
    *(uint4*)&sA[srow*LDSS + scol + 8]  = av1;
    *(short8*)&sB[srow*LDSS + scol]     = pack8(b0, b1);
    *(short8*)&sB[srow*LDSS + scol + 8] = pack8(b2, b3);
    __syncthreads();

    short8 af[4], bf[4];
    #pragma unroll
    for (int mi = 0; mi < 4; ++mi)
      af[mi] = *(const short8*)&sA[(wm + mi*16 + lr)*LDSS + kq];
    #pragma unroll
    for (int ni = 0; ni < 4; ++ni)
      bf[ni] = *(const short8*)&sB[(wn + ni*16 + lr)*LDSS + kq];
    #pragma unroll
    for (int mi = 0; mi < 4; ++mi)
      #pragma unroll
      for (int ni = 0; ni < 4; ++ni)
        acc[mi][ni] = __builtin_amdgcn_mfma_f32_16x16x32_bf16(af[mi], bf[ni], acc[mi][ni], 0, 0, 0);
  }

  const int rq = (lane >> 4) * 4;
  #pragma unroll
  for (int mi = 0; mi < 4; ++mi){
    #pragma unroll
    for (int r = 0; r < 4; ++r){
      int crow = wm + mi*16 + rq + r;
      int gm = m0 + crow;
      if (gm >= cnt) continue;
      int tok = s_tok[crow];
      float gate = s_gate[crow];
      float* orow = out + (size_t)tok * HIDDEN + n0;
      #pragma unroll
      for (int ni = 0; ni < 4; ++ni)
        atomicAdd(&orow[wn + ni*16 + lr], gate * acc[mi][ni][r]);
    }
  }
}

extern "C" void kernel_launch(void* const* d_in, const int* in_sizes, int n_in,
                              void* d_out, int out_size, void* d_ws, size_t ws_size,
                              hipStream_t stream)
{
  (void)in_sizes; (void)n_in; (void)out_size; (void)ws_size;
  const float* hidden = (const float*)d_in[0];
  const float* logits = (const float*)d_in[1];
  const float* w13    = (const float*)d_in[2];
  const float* w2     = (const float*)d_in[3];
  float* out = (float*)d_out;
  int*   ws_i = (int*)d_ws;
  float* ws_f = (float*)d_ws;
  __hip_bfloat16* act = (__hip_bfloat16*)((char*)d_ws + ACT_BYTE_OFF);

  hipMemsetAsync(d_ws, 0, META_INTS * sizeof(int), stream);
  hipMemsetAsync(d_out, 0, (size_t)NUM_TOKENS * HIDDEN * sizeof(float), stream);

  routing_kernel<<<NUM_TOKENS/256, 256, 0, stream>>>(logits, ws_i, ws_f);
  scan_kernel<<<1, 64, 0, stream>>>(ws_i);
  scatter_kernel<<<NUM_TOKENS/256, 256, 0, stream>>>(ws_i, ws_f);
  gemm1_kernel<<<dim3(INTER/BN, NUM_TOKENS/BM, NEXP), 256, 0, stream>>>(hidden, w13, ws_i, act);
  gemm2_kernel<<<dim3(HIDDEN/BN, NUM_TOKENS/BM, NEXP), 256, 0, stream>>>(act, w2, ws_i, ws_f, out);
}